// Round 2
// baseline (435.798 us; speedup 1.0000x reference)
//
#include <hip/hip_runtime.h>
#include <hip/hip_bf16.h>

typedef unsigned short u16;
typedef unsigned int u32;
typedef __bf16 bf16x8 __attribute__((ext_vector_type(8)));
typedef float f32x4 __attribute__((ext_vector_type(4)));
typedef u16 u16x4 __attribute__((ext_vector_type(4)));
typedef u16 u16x8 __attribute__((ext_vector_type(8)));

#define D_IN 4096
#define D_OUT 4096
#define M_TOT 8192
#define RANK_ 16

#define BM 256
#define BN 256
#define BK 64
#define NT (D_IN / BK)   // 64 K-tiles
#define OPB 8            // dequant rows per block

__device__ __forceinline__ u16 f2bf(float f) {
    union { float f; u32 u; } v; v.f = f;
    u32 u = v.u;
    u32 r = (u + 0x7FFFu + ((u >> 16) & 1u)) >> 16;  // round-to-nearest-even
    return (u16)r;
}

// W_eff[o,i] = q[o,i]*scale[o] + min[o] + 2*sum_r B[o,r]*A[r,i]  -> bf16
// 8 rows per block: the 16 A float4 loads amortize across 8 output rows.
__global__ void dequant_fold_kernel(const int* __restrict__ q,
                                    const float* __restrict__ wmin,
                                    const float* __restrict__ wscale,
                                    const float* __restrict__ A,
                                    const float* __restrict__ Bm,
                                    u16* __restrict__ Wb) {
    const int K = D_IN;
    int o0 = blockIdx.x * OPB;
    __shared__ float Br[OPB][RANK_];
    __shared__ float sc_s[OPB], mn_s[OPB];
    if (threadIdx.x < OPB * RANK_) {
        int oo = threadIdx.x >> 4, r = threadIdx.x & 15;
        Br[oo][r] = 2.0f * Bm[(size_t)(o0 + oo) * RANK_ + r];
    }
    if (threadIdx.x < OPB) {
        sc_s[threadIdx.x] = wscale[o0 + threadIdx.x];
        mn_s[threadIdx.x] = wmin[o0 + threadIdx.x];
    }
    __syncthreads();
    for (int i4 = threadIdx.x; i4 < K / 4; i4 += blockDim.x) {
        int i = i4 * 4;
        float4 av[RANK_];
        #pragma unroll
        for (int r = 0; r < RANK_; ++r) av[r] = *(const float4*)(A + (size_t)r * K + i);
        #pragma unroll
        for (int oo = 0; oo < OPB; ++oo) {
            int4 qv = *(const int4*)(q + (size_t)(o0 + oo) * K + i);
            float s = sc_s[oo], m = mn_s[oo];
            float v0 = (float)qv.x * s + m;
            float v1 = (float)qv.y * s + m;
            float v2 = (float)qv.z * s + m;
            float v3 = (float)qv.w * s + m;
            #pragma unroll
            for (int r = 0; r < RANK_; ++r) {
                float br = Br[oo][r];
                v0 += br * av[r].x; v1 += br * av[r].y;
                v2 += br * av[r].z; v3 += br * av[r].w;
            }
            u16x4 ov;
            ov.x = f2bf(v0); ov.y = f2bf(v1); ov.z = f2bf(v2); ov.w = f2bf(v3);
            *(u16x4*)(Wb + (size_t)(o0 + oo) * K + i) = ov;
        }
    }
}

// fp32 -> bf16, 8 elems/thread
__global__ void xcast_kernel(const float* __restrict__ x, u16* __restrict__ xb) {
    size_t i = (size_t)blockIdx.x * blockDim.x + threadIdx.x;
    const float4* p = (const float4*)x + i * 2;
    float4 a = p[0];
    float4 b = p[1];
    u16x8 o;
    o[0] = f2bf(a.x); o[1] = f2bf(a.y); o[2] = f2bf(a.z); o[3] = f2bf(a.w);
    o[4] = f2bf(b.x); o[5] = f2bf(b.y); o[6] = f2bf(b.z); o[7] = f2bf(b.w);
    *(u16x8*)(xb + i * 8) = o;
}

// ---- 256x256 8-phase GEMM: C[M,N] = Xb[M,K] * Wb[N,K]^T + bias ----
// 8 waves (2M x 4N), BK=64, LDS 128KiB = dbuf x (A[256][64] + B[256][64]) bf16.
// T2: 16B-slot XOR-swizzle (slot ^= row&7), applied on global source + ds_read.
// T3/T4: 4 phases/K-tile, stage B(t+2)@P3, A(t+2)@P4, vmcnt(8) once per tile.
// T5: setprio around MFMA clusters.  T1: XCD-aware block swizzle.

#define STAGE_A(pbuf, kt) do { _Pragma("unroll") \
    for (int j_ = 0; j_ < 4; ++j_) \
        __builtin_amdgcn_global_load_lds( \
            (__attribute__((address_space(1))) u32*)(srcA[j_] + (kt) * 64), \
            (__attribute__((address_space(3))) u32*)(smem + (pbuf) * 32768 + ldsA[j_]), \
            16, 0, 0); } while (0)

#define STAGE_B(pbuf, kt) do { _Pragma("unroll") \
    for (int j_ = 0; j_ < 4; ++j_) \
        __builtin_amdgcn_global_load_lds( \
            (__attribute__((address_space(1))) u32*)(srcB[j_] + (kt) * 64), \
            (__attribute__((address_space(3))) u32*)(smem + 65536 + (pbuf) * 32768 + ldsB[j_]), \
            16, 0, 0); } while (0)

#define MFMA(d, va, vb) d = __builtin_amdgcn_mfma_f32_16x16x32_bf16(va, vb, d, 0, 0, 0)

__global__ __launch_bounds__(512, 2) void gemm_bt_kernel(const u16* __restrict__ Xb,
                                                         const u16* __restrict__ Wb,
                                                         const float* __restrict__ bias,
                                                         float* __restrict__ out) {
    extern __shared__ __align__(16) char smem[];   // 131072 B
    const int K = D_IN, N = D_OUT;

    int bid = blockIdx.x;                  // 512 blocks
    int swz = (bid & 7) * 64 + (bid >> 3); // XCD swizzle, bijective (512 % 8 == 0)
    int tM = swz >> 4;                     // 32 M-tiles
    int tN = swz & 15;                     // 16 N-tiles

    int t = threadIdx.x;
    int lane = t & 63;
    int wave = t >> 6;
    int wm = wave >> 2;                    // 0..1
    int wn = wave & 3;                     // 0..3
    int lr = lane & 15;
    int hi = lane >> 4;
    int l7 = lane & 7;

    // ds_read byte offsets: row*128 + swizzled 16B slot. frag row%8 == lane&7.
    int xs0 = ((0 * 4 + hi) ^ l7) << 4;    // ks=0
    int xs1 = ((1 * 4 + hi) ^ l7) << 4;    // ks=1
    int aRow = (wm * 128 + lr) * 128;      // + mf*2048
    int bRow = (wn * 64 + lr) * 128;       // + nf*2048

    // staging: thread stages 4x16B per tile per operand; chunk c = t + j*512
    // LDS dest linear (c*16); global source slot pre-XORed with row&7 (rule 21).
    const u16* srcA[4]; const u16* srcB[4]; int ldsA[4]; int ldsB[4];
    #pragma unroll
    for (int j = 0; j < 4; ++j) {
        int c = t + j * 512;
        int row = c >> 3, slot = c & 7;
        int sslot = slot ^ (row & 7);
        srcA[j] = Xb + (size_t)(tM * 256 + row) * K + (sslot << 3);
        srcB[j] = Wb + (size_t)(tN * 256 + row) * K + (sslot << 3);
        ldsA[j] = c * 16;
        ldsB[j] = c * 16;
    }

    f32x4 acc[8][4];
    #pragma unroll
    for (int i = 0; i < 8; ++i)
        #pragma unroll
        for (int j = 0; j < 4; ++j)
            acc[i][j] = (f32x4){0.f, 0.f, 0.f, 0.f};

    // prologue: tile0 -> buf0, tile1 -> buf1; wait for tile0 (8 newest in flight)
    STAGE_A(0, 0); STAGE_B(0, 0);
    STAGE_A(1, 1); STAGE_B(1, 1);
    asm volatile("s_waitcnt vmcnt(8)" ::: "memory");
    __builtin_amdgcn_s_barrier();

    bf16x8 a[4][2], b[4][2];

    for (int tt = 0; tt < NT; ++tt) {
        int pA = (tt & 1) * 32768;
        int pB = 65536 + (tt & 1) * 32768;

        // ---- P1: read A frags 0-3 + B frags 0-1; MFMA quadrant (m0-3, n0-1)
        #pragma unroll
        for (int mf = 0; mf < 4; ++mf) {
            a[mf][0] = *(const bf16x8*)(smem + pA + aRow + mf * 2048 + xs0);
            a[mf][1] = *(const bf16x8*)(smem + pA + aRow + mf * 2048 + xs1);
        }
        #pragma unroll
        for (int nf = 0; nf < 2; ++nf) {
            b[nf][0] = *(const bf16x8*)(smem + pB + bRow + nf * 2048 + xs0);
            b[nf][1] = *(const bf16x8*)(smem + pB + bRow + nf * 2048 + xs1);
        }
        __builtin_amdgcn_s_barrier();
        asm volatile("s_waitcnt lgkmcnt(0)");
        __builtin_amdgcn_s_setprio(1);
        #pragma unroll
        for (int mf = 0; mf < 4; ++mf)
            #pragma unroll
            for (int nf = 0; nf < 2; ++nf) {
                MFMA(acc[mf][nf], a[mf][0], b[nf][0]);
                MFMA(acc[mf][nf], a[mf][1], b[nf][1]);
            }
        __builtin_amdgcn_s_setprio(0);
        __builtin_amdgcn_s_barrier();

        // ---- P2: read B frags 2-3; MFMA quadrant (m0-3, n2-3)
        #pragma unroll
        for (int nf = 2; nf < 4; ++nf) {
            b[nf][0] = *(const bf16x8*)(smem + pB + bRow + nf * 2048 + xs0);
            b[nf][1] = *(const bf16x8*)(smem + pB + bRow + nf * 2048 + xs1);
        }
        __builtin_amdgcn_s_barrier();
        asm volatile("s_waitcnt lgkmcnt(0)");
        __builtin_amdgcn_s_setprio(1);
        #pragma unroll
        for (int mf = 0; mf < 4; ++mf)
            #pragma unroll
            for (int nf = 2; nf < 4; ++nf) {
                MFMA(acc[mf][nf], a[mf][0], b[nf][0]);
                MFMA(acc[mf][nf], a[mf][1], b[nf][1]);
            }
        __builtin_amdgcn_s_setprio(0);
        __builtin_amdgcn_s_barrier();

        // ---- P3: read A frags 4-7; stage B(tt+2); MFMA quadrant (m4-7, n2-3)
        #pragma unroll
        for (int mf = 0; mf < 4; ++mf) {
            a[mf][0] = *(const bf16x8*)(smem + pA + aRow + (mf + 4) * 2048 + xs0);
            a[mf][1] = *(const bf16x8*)(smem + pA + aRow + (mf + 4) * 2048 + xs1);
        }
        if (tt + 2 < NT) { STAGE_B((tt & 1), tt + 2); }
        __builtin_amdgcn_s_barrier();
        asm volatile("s_waitcnt lgkmcnt(0)");
        __builtin_amdgcn_s_setprio(1);
        #pragma unroll
        for (int mf = 0; mf < 4; ++mf)
            #pragma unroll
            for (int nf = 2; nf < 4; ++nf) {
                MFMA(acc[mf + 4][nf], a[mf][0], b[nf][0]);
                MFMA(acc[mf + 4][nf], a[mf][1], b[nf][1]);
            }
        __builtin_amdgcn_s_setprio(0);
        __builtin_amdgcn_s_barrier();

        // ---- P4: stage A(tt+2); counted vmcnt; MFMA quadrant (m4-7, n0-1)
        if (tt + 2 < NT) { STAGE_A((tt & 1), tt + 2); }
        if (tt < NT - 2) { asm volatile("s_waitcnt vmcnt(8)" ::: "memory"); }
        else             { asm volatile("s_waitcnt vmcnt(0)" ::: "memory"); }
        __builtin_amdgcn_s_barrier();
        __builtin_amdgcn_s_setprio(1);
        #pragma unroll
        for (int mf = 0; mf < 4; ++mf)
            #pragma unroll
            for (int nf = 0; nf < 2; ++nf) {
                MFMA(acc[mf + 4][nf], a[mf][0], b[nf][0]);
                MFMA(acc[mf + 4][nf], a[mf][1], b[nf][1]);
            }
        __builtin_amdgcn_s_setprio(0);
        __builtin_amdgcn_s_barrier();
    }

    // epilogue: C/D layout col=lane&15, row=(lane>>4)*4+reg
    #pragma unroll
    for (int nf = 0; nf < 4; ++nf) {
        int gn = tN * 256 + wn * 64 + nf * 16 + lr;
        float bs = bias[gn];
        #pragma unroll
        for (int mf = 0; mf < 8; ++mf) {
            #pragma unroll
            for (int r = 0; r < 4; ++r) {
                int gm = tM * 256 + wm * 128 + mf * 16 + hi * 4 + r;
                out[(size_t)gm * N + gn] = acc[mf][nf][r] + bs;
            }
        }
    }
}

extern "C" void kernel_launch(void* const* d_in, const int* in_sizes, int n_in,
                              void* d_out, int out_size, void* d_ws, size_t ws_size,
                              hipStream_t stream) {
    (void)in_sizes; (void)n_in; (void)out_size; (void)ws_size;
    const float* x      = (const float*)d_in[0];
    const int*   qw     = (const int*)d_in[1];
    const float* wmin   = (const float*)d_in[2];
    const float* wscale = (const float*)d_in[3];
    const float* bias   = (const float*)d_in[4];
    const float* A      = (const float*)d_in[5];
    const float* Bm     = (const float*)d_in[6];
    float* out = (float*)d_out;

    u16* Wb = (u16*)d_ws;                         // 4096*4096*2 = 33.5 MB
    u16* Xb = Wb + (size_t)D_OUT * D_IN;          // 8192*4096*2 = 67.1 MB

    dequant_fold_kernel<<<D_OUT / OPB, 256, 0, stream>>>(qw, wmin, wscale, A, Bm, Wb);
    xcast_kernel<<<(M_TOT * D_IN) / (256 * 8), 256, 0, stream>>>(x, Xb);
    gemm_bt_kernel<<<(M_TOT / BM) * (D_OUT / BN), 512, 131072, stream>>>(Xb, Wb, bias, out);
}

// Round 3
// 311.758 us; speedup vs baseline: 1.3979x; 1.3979x over previous
//
#include <hip/hip_runtime.h>
#include <hip/hip_bf16.h>

typedef unsigned short u16;
typedef unsigned int u32;
typedef __bf16 bf16x8 __attribute__((ext_vector_type(8)));
typedef float f32x4 __attribute__((ext_vector_type(4)));
typedef u16 u16x4 __attribute__((ext_vector_type(4)));
typedef u16 u16x8 __attribute__((ext_vector_type(8)));

#define D_IN 4096
#define D_OUT 4096
#define M_TOT 8192
#define RANK_ 16

#define BM 256
#define BN 256
#define BK 64
#define NT (D_IN / BK)   // 64 K-tiles
#define OPB 2            // dequant rows per block (2: live-set ~70 regs, no spill)

__device__ __forceinline__ u16 f2bf(float f) {
    union { float f; u32 u; } v; v.f = f;
    u32 u = v.u;
    u32 r = (u + 0x7FFFu + ((u >> 16) & 1u)) >> 16;  // round-to-nearest-even
    return (u16)r;
}

// W_eff[o,i] = q[o,i]*scale[o] + min[o] + 2*sum_r B[o,r]*A[r,i]  -> bf16
// OPB=2 rows/block: A float4 loads amortize 2x, live set stays ~70 regs.
__global__ __launch_bounds__(256) void dequant_fold_kernel(
        const int* __restrict__ q, const float* __restrict__ wmin,
        const float* __restrict__ wscale, const float* __restrict__ A,
        const float* __restrict__ Bm, u16* __restrict__ Wb) {
    const int K = D_IN;
    int o0 = blockIdx.x * OPB;
    float s0 = wscale[o0], s1 = wscale[o0 + 1];
    float m0 = wmin[o0],   m1 = wmin[o0 + 1];
    float Br0[RANK_], Br1[RANK_];   // block-uniform -> SGPRs
    #pragma unroll
    for (int r = 0; r < RANK_; ++r) {
        Br0[r] = 2.0f * Bm[(size_t)o0 * RANK_ + r];
        Br1[r] = 2.0f * Bm[(size_t)(o0 + 1) * RANK_ + r];
    }
    for (int i4 = threadIdx.x; i4 < K / 4; i4 += 256) {
        int i = i4 * 4;
        int4 q0 = *(const int4*)(q + (size_t)o0 * K + i);
        int4 q1 = *(const int4*)(q + (size_t)(o0 + 1) * K + i);
        float v00 = (float)q0.x * s0 + m0, v01 = (float)q0.y * s0 + m0;
        float v02 = (float)q0.z * s0 + m0, v03 = (float)q0.w * s0 + m0;
        float v10 = (float)q1.x * s1 + m1, v11 = (float)q1.y * s1 + m1;
        float v12 = (float)q1.z * s1 + m1, v13 = (float)q1.w * s1 + m1;
        #pragma unroll
        for (int r = 0; r < RANK_; ++r) {
            float4 av = *(const float4*)(A + (size_t)r * K + i);
            v00 += Br0[r] * av.x; v01 += Br0[r] * av.y;
            v02 += Br0[r] * av.z; v03 += Br0[r] * av.w;
            v10 += Br1[r] * av.x; v11 += Br1[r] * av.y;
            v12 += Br1[r] * av.z; v13 += Br1[r] * av.w;
        }
        u16x4 o0v, o1v;
        o0v.x = f2bf(v00); o0v.y = f2bf(v01); o0v.z = f2bf(v02); o0v.w = f2bf(v03);
        o1v.x = f2bf(v10); o1v.y = f2bf(v11); o1v.z = f2bf(v12); o1v.w = f2bf(v13);
        *(u16x4*)(Wb + (size_t)o0 * K + i) = o0v;
        *(u16x4*)(Wb + (size_t)(o0 + 1) * K + i) = o1v;
    }
}

// fp32 -> bf16, 8 elems/thread
__global__ void xcast_kernel(const float* __restrict__ x, u16* __restrict__ xb) {
    size_t i = (size_t)blockIdx.x * blockDim.x + threadIdx.x;
    const float4* p = (const float4*)x + i * 2;
    float4 a = p[0];
    float4 b = p[1];
    u16x8 o;
    o[0] = f2bf(a.x); o[1] = f2bf(a.y); o[2] = f2bf(a.z); o[3] = f2bf(a.w);
    o[4] = f2bf(b.x); o[5] = f2bf(b.y); o[6] = f2bf(b.z); o[7] = f2bf(b.w);
    *(u16x8*)(xb + i * 8) = o;
}

// ---- 256x256 8-phase GEMM: C[M,N] = Xb[M,K] * Wb[N,K]^T + bias ----
// 8 waves (2M x 4N), BK=64, LDS 128KiB dbuf.  T1 XCD swizzle, T2 XOR swizzle
// (0 conflicts measured), T3/T4 counted vmcnt, T5 setprio.
// Staging spread by half-region lifetime:
//   P2: A-mf03 + B-nf01 (read-complete after P1)   [4 loads]
//   P3: B-nf23          (read-complete after P2)   [2 loads]
//   P4: A-mf47          (read-complete after P3)   [2 loads]

#define STAGE2(srcarr, ldsarr, base, j0, kt) do { _Pragma("unroll") \
    for (int j_ = (j0); j_ < (j0) + 2; ++j_) \
        __builtin_amdgcn_global_load_lds( \
            (__attribute__((address_space(1))) u32*)(srcarr[j_] + (kt) * 64), \
            (__attribute__((address_space(3))) u32*)(smem + (base) + ldsarr[j_]), \
            16, 0, 0); } while (0)

#define MFMA(d, va, vb) d = __builtin_amdgcn_mfma_f32_16x16x32_bf16(va, vb, d, 0, 0, 0)

__global__ __launch_bounds__(512, 2) void gemm_bt_kernel(const u16* __restrict__ Xb,
                                                         const u16* __restrict__ Wb,
                                                         const float* __restrict__ bias,
                                                         float* __restrict__ out) {
    extern __shared__ __align__(16) char smem[];   // 131072 B
    const int K = D_IN, N = D_OUT;

    int bid = blockIdx.x;                  // 512 blocks
    int swz = (bid & 7) * 64 + (bid >> 3); // XCD swizzle, bijective (512 % 8 == 0)
    int tM = swz >> 4;                     // 32 M-tiles
    int tN = swz & 15;                     // 16 N-tiles

    int t = threadIdx.x;
    int lane = t & 63;
    int wave = t >> 6;
    int wm = wave >> 2;                    // 0..1
    int wn = wave & 3;                     // 0..3
    int lr = lane & 15;
    int hi = lane >> 4;
    int l7 = lane & 7;

    // ds_read byte offsets: row*128 + swizzled 16B slot (slot ^= row&7).
    int xs0 = ((0 * 4 + hi) ^ l7) << 4;    // ks=0
    int xs1 = ((1 * 4 + hi) ^ l7) << 4;    // ks=1
    int aRow = (wm * 128 + lr) * 128;      // + mf*2048
    int bRow = (wn * 64 + lr) * 128;       // + nf*2048

    // Staging chunk lists (chunk = 16B; LDS dest linear c*16, global source
    // slot pre-XORed with row&7 — rule 21 both-sides).
    //  A pairs: [0,1] = mf03 rows {0-63,128-191};  [2,3] = mf47 rows {64-127,192-255}
    //  B pairs: [0,1] = nf01 rows {wn*64+[0,32)};  [2,3] = nf23 rows {wn*64+[32,64)}
    const u16* srcA[4]; const u16* srcB[4]; int ldsA[4]; int ldsB[4];
    {
        int cA[4] = { t, 1024 + t, 512 + t, 1536 + t };
        int b0 = (t & 255) + ((t >> 8) << 9);
        int cB[4] = { b0, b0 + 1024, b0 + 256, b0 + 1280 };
        #pragma unroll
        for (int j = 0; j < 4; ++j) {
            int ca = cA[j], cb = cB[j];
            int rowa = ca >> 3, rowb = cb >> 3;
            int sa = (ca & 7) ^ (rowa & 7);
            int sb = (cb & 7) ^ (rowb & 7);
            srcA[j] = Xb + (size_t)(tM * 256 + rowa) * K + (sa << 3);
            srcB[j] = Wb + (size_t)(tN * 256 + rowb) * K + (sb << 3);
            ldsA[j] = ca * 16;
            ldsB[j] = cb * 16;
        }
    }

    f32x4 acc[8][4];
    #pragma unroll
    for (int i = 0; i < 8; ++i)
        #pragma unroll
        for (int j = 0; j < 4; ++j)
            acc[i][j] = (f32x4){0.f, 0.f, 0.f, 0.f};

    // prologue: tile0 -> buf0, tile1 -> buf1; wait tile0 (8 newest stay in flight)
    STAGE2(srcA, ldsA, 0,     0, 0); STAGE2(srcA, ldsA, 0,     2, 0);
    STAGE2(srcB, ldsB, 65536, 0, 0); STAGE2(srcB, ldsB, 65536, 2, 0);
    STAGE2(srcA, ldsA, 32768, 0, 1); STAGE2(srcA, ldsA, 32768, 2, 1);
    STAGE2(srcB, ldsB, 98304, 0, 1); STAGE2(srcB, ldsB, 98304, 2, 1);
    asm volatile("s_waitcnt vmcnt(8)" ::: "memory");
    __builtin_amdgcn_s_barrier();

    bf16x8 a[4][2], b[4][2];

    for (int tt = 0; tt < NT; ++tt) {
        int pA = (tt & 1) * 32768;
        int pB = 65536 + (tt & 1) * 32768;
        bool pre = (tt + 2 < NT);

        // ---- P1: read a[0-3], b[0-1]; MFMA (m0-3, n0-1)
        #pragma unroll
        for (int mf = 0; mf < 4; ++mf) {
            a[mf][0] = *(const bf16x8*)(smem + pA + aRow + mf * 2048 + xs0);
            a[mf][1] = *(const bf16x8*)(smem + pA + aRow + mf * 2048 + xs1);
        }
        #pragma unroll
        for (int nf = 0; nf < 2; ++nf) {
            b[nf][0] = *(const bf16x8*)(smem + pB + bRow + nf * 2048 + xs0);
            b[nf][1] = *(const bf16x8*)(smem + pB + bRow + nf * 2048 + xs1);
        }
        asm volatile("s_waitcnt lgkmcnt(8)" ::: "memory");   // 12 reads issued
        __builtin_amdgcn_s_barrier();
        asm volatile("s_waitcnt lgkmcnt(0)");
        __builtin_amdgcn_s_setprio(1);
        #pragma unroll
        for (int mf = 0; mf < 4; ++mf)
            #pragma unroll
            for (int nf = 0; nf < 2; ++nf) {
                MFMA(acc[mf][nf], a[mf][0], b[nf][0]);
                MFMA(acc[mf][nf], a[mf][1], b[nf][1]);
            }
        __builtin_amdgcn_s_setprio(0);
        __builtin_amdgcn_s_barrier();

        // ---- P2: read b[2-3]; stage A-mf03(tt+2) + B-nf01(tt+2); MFMA (m0-3, n2-3)
        #pragma unroll
        for (int nf = 2; nf < 4; ++nf) {
            b[nf][0] = *(const bf16x8*)(smem + pB + bRow + nf * 2048 + xs0);
            b[nf][1] = *(const bf16x8*)(smem + pB + bRow + nf * 2048 + xs1);
        }
        if (pre) {
            STAGE2(srcA, ldsA, pA, 0, tt + 2);
            STAGE2(srcB, ldsB, pB, 0, tt + 2);
        }
        __builtin_amdgcn_s_barrier();
        asm volatile("s_waitcnt lgkmcnt(0)");
        __builtin_amdgcn_s_setprio(1);
        #pragma unroll
        for (int mf = 0; mf < 4; ++mf)
            #pragma unroll
            for (int nf = 2; nf < 4; ++nf) {
                MFMA(acc[mf][nf], a[mf][0], b[nf][0]);
                MFMA(acc[mf][nf], a[mf][1], b[nf][1]);
            }
        __builtin_amdgcn_s_setprio(0);
        __builtin_amdgcn_s_barrier();

        // ---- P3: read a[4-7]; stage B-nf23(tt+2); MFMA (m4-7, n2-3)
        #pragma unroll
        for (int mf = 0; mf < 4; ++mf) {
            a[mf][0] = *(const bf16x8*)(smem + pA + aRow + (mf + 4) * 2048 + xs0);
            a[mf][1] = *(const bf16x8*)(smem + pA + aRow + (mf + 4) * 2048 + xs1);
        }
        if (pre) { STAGE2(srcB, ldsB, pB, 2, tt + 2); }
        __builtin_amdgcn_s_barrier();
        asm volatile("s_waitcnt lgkmcnt(0)");
        __builtin_amdgcn_s_setprio(1);
        #pragma unroll
        for (int mf = 0; mf < 4; ++mf)
            #pragma unroll
            for (int nf = 2; nf < 4; ++nf) {
                MFMA(acc[mf + 4][nf], a[mf][0], b[nf][0]);
                MFMA(acc[mf + 4][nf], a[mf][1], b[nf][1]);
            }
        __builtin_amdgcn_s_setprio(0);
        __builtin_amdgcn_s_barrier();

        // ---- P4: stage A-mf47(tt+2); counted vmcnt; MFMA (m4-7, n0-1)
        if (pre) { STAGE2(srcA, ldsA, pA, 2, tt + 2); }
        if (tt < NT - 2) { asm volatile("s_waitcnt vmcnt(8)" ::: "memory"); }
        else             { asm volatile("s_waitcnt vmcnt(0)" ::: "memory"); }
        __builtin_amdgcn_s_barrier();
        __builtin_amdgcn_s_setprio(1);
        #pragma unroll
        for (int mf = 0; mf < 4; ++mf)
            #pragma unroll
            for (int nf = 0; nf < 2; ++nf) {
                MFMA(acc[mf + 4][nf], a[mf][0], b[nf][0]);
                MFMA(acc[mf + 4][nf], a[mf][1], b[nf][1]);
            }
        __builtin_amdgcn_s_setprio(0);
        __builtin_amdgcn_s_barrier();
    }

    // epilogue: C/D layout col=lane&15, row=(lane>>4)*4+reg
    #pragma unroll
    for (int nf = 0; nf < 4; ++nf) {
        int gn = tN * 256 + wn * 64 + nf * 16 + lr;
        float bs = bias[gn];
        #pragma unroll
        for (int mf = 0; mf < 8; ++mf) {
            #pragma unroll
            for (int r = 0; r < 4; ++r) {
                int gm = tM * 256 + wm * 128 + mf * 16 + hi * 4 + r;
                out[(size_t)gm * N + gn] = acc[mf][nf][r] + bs;
            }
        }
    }
}

extern "C" void kernel_launch(void* const* d_in, const int* in_sizes, int n_in,
                              void* d_out, int out_size, void* d_ws, size_t ws_size,
                              hipStream_t stream) {
    (void)in_sizes; (void)n_in; (void)out_size; (void)ws_size;
    const float* x      = (const float*)d_in[0];
    const int*   qw     = (const int*)d_in[1];
    const float* wmin   = (const float*)d_in[2];
    const float* wscale = (const float*)d_in[3];
    const float* bias   = (const float*)d_in[4];
    const float* A      = (const float*)d_in[5];
    const float* Bm     = (const float*)d_in[6];
    float* out = (float*)d_out;

    u16* Wb = (u16*)d_ws;                         // 4096*4096*2 = 33.5 MB
    u16* Xb = Wb + (size_t)D_OUT * D_IN;          // 8192*4096*2 = 67.1 MB

    dequant_fold_kernel<<<D_OUT / OPB, 256, 0, stream>>>(qw, wmin, wscale, A, Bm, Wb);
    xcast_kernel<<<(M_TOT * D_IN) / (256 * 8), 256, 0, stream>>>(x, Xb);
    gemm_bt_kernel<<<(M_TOT / BM) * (D_OUT / BN), 512, 131072, stream>>>(Xb, Wb, bias, out);
}